// Round 6
// baseline (128.285 us; speedup 1.0000x reference)
//
#include <hip/hip_runtime.h>
#include <math.h>

#define NB 32
#define NP 4096
#define NS 128
#define DI 512
#define DV 512
#define DP 768
#define NH 4
#define DC 1024
#define DH 256

// clang native vector (supports .xyzw, elementwise ops, scalar splat)
typedef float f4 __attribute__((ext_vector_type(4)));

// ---------------------------------------------------------------------------
// Kernel 1 (fused): per block (b,h):
//   q[d]           = dot(h_concat[b,:], qW[h,d,:]) + qb[h,d]   (LDS only)
//   w_part[b,h,c]  = (1/H) * sum_d q[d] * kW[h,d,c]            (owned slice)
//   bavg_part[b,h] = (1/H) * sum_d q[d] * kb[h,d]
// Also zeroes acc[] (kernel boundary orders this before k_score's atomics).
// grid = NB*NH = 128 blocks, 256 threads.
// ---------------------------------------------------------------------------
__global__ __launch_bounds__(256) void k_qw(const float* __restrict__ h_int,
                                            const float* __restrict__ h_vc,
                                            const float* __restrict__ qW,
                                            const float* __restrict__ qb,
                                            const float* __restrict__ kW,
                                            const float* __restrict__ kb,
                                            float* __restrict__ w_part,
                                            float* __restrict__ bavg_part,
                                            float* __restrict__ acc) {
    int b = blockIdx.x / NH, h = blockIdx.x % NH;
    int tid = threadIdx.x;

    // zero the k_score accumulator (4128 elements < 128*256 threads)
    int g = blockIdx.x * 256 + tid;
    if (g < NB * (NS + 1)) acc[g] = 0.f;

    __shared__ float hc[DC];
    __shared__ float qs[DH];
    for (int i = tid; i < DI; i += 256) hc[i] = h_int[b * DI + i];
    for (int i = tid; i < DV; i += 256) hc[DI + i] = h_vc[b * DV + i];
    __syncthreads();

    // phase 1: q[d=tid]
    const float* w = qW + (size_t)(h * DH + tid) * DC;
    float acc_q = qb[h * DH + tid];
#pragma unroll 8
    for (int c = 0; c < DC; c += 4) {
        f4 wv = *(const f4*)(w + c);
        acc_q += wv.x * hc[c] + wv.y * hc[c + 1] + wv.z * hc[c + 2] + wv.w * hc[c + 3];
    }
    qs[tid] = acc_q;
    __syncthreads();

    // phase 2: f4-vectorized contraction. Threads 0..191 (waves 0-2) each own
    // one f4 column group c4 = tid (cols 4t..4t+3): 1 KB/wave-instruction
    // coalescing, 4x fewer memory instructions than scalar. Per-column
    // summation order identical to scalar version -> bitwise-same result.
    const float inv_h = 1.0f / NH;
    if (tid < DP / 4) {
        f4 wacc = 0.f;
        const float* kbase = kW + (size_t)(h * DH) * DP + 4 * tid;
#pragma unroll 8
        for (int i = 0; i < DH; ++i) {
            f4 kv = *(const f4*)(kbase + (size_t)i * DP);
            wacc += qs[i] * kv;
        }
        *(f4*)(w_part + (size_t)(b * NH + h) * DP + 4 * tid) = wacc * inv_h;
    }

    // bias partial: sum_d qs[d]*kb[h,d]
    float pb = qs[tid] * kb[h * DH + tid];
#pragma unroll
    for (int off = 32; off > 0; off >>= 1) pb += __shfl_xor(pb, off);
    __shared__ float red[4];
    int wave = tid >> 6, lane = tid & 63;
    if (lane == 0) red[wave] = pb;
    __syncthreads();
    if (tid == 0) bavg_part[b * NH + h] = (red[0] + red[1] + red[2] + red[3]) * inv_h;
}

// ---------------------------------------------------------------------------
// Kernel 2 (heavy, streaming): register run-accumulation of patch-row vector
// sums; dot+reduce+atomic only at segment crossings (monotone advance).
// 2-row-deep software pipeline (6 KB in flight per wave), PPW=32 rows/wave.
// R6: plain loads (nt hint removed), no min-waves bound (VGPR cap removed).
// grid = NB*CHUNKS (CHUNKS=32 -> 1024 blocks), 256 threads.
// ---------------------------------------------------------------------------
__global__ __launch_bounds__(256) void k_score(const float* __restrict__ patch,
                                               const float* __restrict__ w_part,
                                               const int* __restrict__ bnd,
                                               float* __restrict__ acc) {
    constexpr int CHUNKS = 32;
    constexpr int PPB = NP / CHUNKS;  // 128 patches per block
    constexpr int PPW = PPB / 4;      // 32 patches per wave
    constexpr int RS = DP / 4;        // row stride in f4 (192)
    int b = blockIdx.x / CHUNKS;
    int chunk = blockIdx.x % CHUNKS;
    __shared__ int bsh[NS + 1];
    int tid = threadIdx.x;
    if (tid <= NS) bsh[tid] = bnd[tid];
    __syncthreads();
    int wave = tid >> 6, lane = tid & 63;

    // weights: sum the 4 per-head partials (L2-hot)
    const f4* wp = (const f4*)(w_part + (size_t)b * NH * DP);
    f4 w0 = 0.f, w1 = 0.f, w2 = 0.f;
#pragma unroll
    for (int h = 0; h < NH; ++h) {
        w0 += wp[h * RS + lane];
        w1 += wp[h * RS + 64 + lane];
        w2 += wp[h * RS + 128 + lane];
    }
    float* accb = acc + (size_t)b * (NS + 1);

    int p0 = chunk * PPB + wave * PPW;

    // initial segment: largest i with bsh[i] <= p0; dump = NS
    int cur, nxt;
    if (p0 < bsh[0]) {
        cur = NS; nxt = bsh[0];
    } else {
        int lo = 0, hi = NS;
        while (lo < hi) {
            int mid = (lo + hi + 1) >> 1;
            if (bsh[mid] <= p0) lo = mid; else hi = mid - 1;
        }
        cur = lo;
        nxt = (cur < NS) ? bsh[cur + 1] : NP;
    }

    f4 r0 = 0.f, r1 = 0.f, r2 = 0.f;
    const f4* base = (const f4*)(patch + ((size_t)b * NP + p0) * DP);

#define LOADROW(dst0, dst1, dst2, i)                                          \
    {                                                                         \
        const f4* rp_ = base + (size_t)(i) * RS;                              \
        dst0 = rp_[lane];                                                     \
        dst1 = rp_[64 + lane];                                                \
        dst2 = rp_[128 + lane];                                               \
    }

#define PROCROW(s0, s1, s2, i)                                                \
    {                                                                         \
        int p_ = p0 + (i);                                                    \
        if (p_ >= nxt) { /* wave-uniform: flush run, advance segment */       \
            f4 sv = r0 * w0 + r1 * w1 + r2 * w2;                              \
            float s = sv.x + sv.y + sv.z + sv.w;                              \
            for (int off_ = 32; off_ > 0; off_ >>= 1) s += __shfl_xor(s, off_); \
            if (lane == 0) atomicAdd(&accb[cur], s);                          \
            r0 = 0.f; r1 = 0.f; r2 = 0.f;                                     \
            cur = (cur == NS) ? 0 : cur + 1;                                  \
            while (cur < NS && bsh[cur + 1] <= p_) cur++;                     \
            nxt = (cur < NS) ? bsh[cur + 1] : NP;                             \
        }                                                                     \
        r0 += s0; r1 += s1; r2 += s2;                                         \
    }

    f4 A0, A1, A2, B0, B1, B2, C0, C1, C2, D0, D1, D2;
    LOADROW(A0, A1, A2, 0)
    LOADROW(B0, B1, B2, 1)
#pragma unroll
    for (int g2 = 0; g2 < PPW - 2; g2 += 2) {
        LOADROW(C0, C1, C2, g2 + 2)
        LOADROW(D0, D1, D2, g2 + 3)
        PROCROW(A0, A1, A2, g2)
        PROCROW(B0, B1, B2, g2 + 1)
        A0 = C0; A1 = C1; A2 = C2;
        B0 = D0; B1 = D1; B2 = D2;
    }
    PROCROW(A0, A1, A2, PPW - 2)
    PROCROW(B0, B1, B2, PPW - 1)

    // final flush
    {
        f4 sv = r0 * w0 + r1 * w1 + r2 * w2;
        float s = sv.x + sv.y + sv.z + sv.w;
#pragma unroll
        for (int off = 32; off > 0; off >>= 1) s += __shfl_xor(s, off);
        if (lane == 0) atomicAdd(&accb[cur], s);
    }
#undef LOADROW
#undef PROCROW
}

// ---------------------------------------------------------------------------
// Kernel 3: out[b,s] = sigmoid(acc[b,s]/cnt + sum_h bavg_part[b,h]) if cnt>0
//           else sigmoid(0)
// ---------------------------------------------------------------------------
__global__ __launch_bounds__(256) void k_out(const float* __restrict__ acc,
                                             const float* __restrict__ bavg_part,
                                             const int* __restrict__ bnd,
                                             float* __restrict__ out) {
    int i = blockIdx.x * 256 + threadIdx.x;  // 0 .. NB*NS-1
    if (i >= NB * NS) return;
    int b = i / NS, s = i % NS;
    int cnt = bnd[s + 1] - bnd[s];
    float v = 0.f;
    if (cnt > 0) {
        float bb = bavg_part[b * NH] + bavg_part[b * NH + 1]
                 + bavg_part[b * NH + 2] + bavg_part[b * NH + 3];
        v = acc[b * (NS + 1) + s] / (float)cnt + bb;
    }
    out[i] = 1.0f / (1.0f + expf(-v));
}

extern "C" void kernel_launch(void* const* d_in, const int* in_sizes, int n_in,
                              void* d_out, int out_size, void* d_ws, size_t ws_size,
                              hipStream_t stream) {
    const float* h_int = (const float*)d_in[0];
    const float* h_vc  = (const float*)d_in[1];
    const float* patch = (const float*)d_in[2];
    const int*   bnd   = (const int*)d_in[3];
    const float* qW    = (const float*)d_in[4];
    const float* qb    = (const float*)d_in[5];
    const float* kW    = (const float*)d_in[6];
    const float* kb    = (const float*)d_in[7];
    float* out = (float*)d_out;

    // workspace: [acc NB*(NS+1)] [w_part NB*NH*DP] [bavg_part NB*NH]
    float* acc       = (float*)d_ws;
    float* w_part    = acc + NB * (NS + 1);
    float* bavg_part = w_part + NB * NH * DP;

    k_qw<<<NB * NH, 256, 0, stream>>>(h_int, h_vc, qW, qb, kW, kb,
                                      w_part, bavg_part, acc);
    k_score<<<NB * 32, 256, 0, stream>>>(patch, w_part, bnd, acc);
    k_out<<<(NB * NS + 255) / 256, 256, 0, stream>>>(acc, bavg_part, bnd, out);
}

// Round 7
// 108.062 us; speedup vs baseline: 1.1871x; 1.1871x over previous
//
#include <hip/hip_runtime.h>
#include <math.h>

#define NB 32
#define NP 4096
#define NS 128
#define DI 512
#define DV 512
#define DP 768
#define NH 4
#define DC 1024
#define DH 256

// clang native vector (required by __builtin_nontemporal_load; supports .xyzw)
typedef float f4 __attribute__((ext_vector_type(4)));

// ---------------------------------------------------------------------------
// Kernel 1 (fused): per block (b,h):
//   q[d]           = dot(h_concat[b,:], qW[h,d,:]) + qb[h,d]   (LDS only)
//   w_part[b,h,c]  = (1/H) * sum_d q[d] * kW[h,d,c]            (owned slice)
//   bavg_part[b,h] = (1/H) * sum_d q[d] * kb[h,d]
// Also zeroes acc[] (kernel boundary orders this before k_score's atomics).
// grid = NB*NH = 128 blocks, 256 threads.
// ---------------------------------------------------------------------------
__global__ __launch_bounds__(256) void k_qw(const float* __restrict__ h_int,
                                            const float* __restrict__ h_vc,
                                            const float* __restrict__ qW,
                                            const float* __restrict__ qb,
                                            const float* __restrict__ kW,
                                            const float* __restrict__ kb,
                                            float* __restrict__ w_part,
                                            float* __restrict__ bavg_part,
                                            float* __restrict__ acc) {
    int b = blockIdx.x / NH, h = blockIdx.x % NH;
    int tid = threadIdx.x;

    // zero the k_score accumulator (4128 elements < 128*256 threads)
    int g = blockIdx.x * 256 + tid;
    if (g < NB * (NS + 1)) acc[g] = 0.f;

    __shared__ float hc[DC];
    __shared__ float qs[DH];
    for (int i = tid; i < DI; i += 256) hc[i] = h_int[b * DI + i];
    for (int i = tid; i < DV; i += 256) hc[DI + i] = h_vc[b * DV + i];
    __syncthreads();

    // phase 1: q[d=tid]
    const float* w = qW + (size_t)(h * DH + tid) * DC;
    float acc_q = qb[h * DH + tid];
#pragma unroll 8
    for (int c = 0; c < DC; c += 4) {
        f4 wv = *(const f4*)(w + c);
        acc_q += wv.x * hc[c] + wv.y * hc[c + 1] + wv.z * hc[c + 2] + wv.w * hc[c + 3];
    }
    qs[tid] = acc_q;
    __syncthreads();

    // phase 2: f4-vectorized contraction. Threads 0..191 (waves 0-2) each own
    // one f4 column group (cols 4t..4t+3): 1 KB/wave-instruction coalescing.
    // Per-column summation order identical to scalar version.
    const float inv_h = 1.0f / NH;
    if (tid < DP / 4) {
        f4 wacc = 0.f;
        const float* kbase = kW + (size_t)(h * DH) * DP + 4 * tid;
#pragma unroll 8
        for (int i = 0; i < DH; ++i) {
            f4 kv = *(const f4*)(kbase + (size_t)i * DP);
            wacc += qs[i] * kv;
        }
        *(f4*)(w_part + (size_t)(b * NH + h) * DP + 4 * tid) = wacc * inv_h;
    }

    // bias partial: sum_d qs[d]*kb[h,d]
    float pb = qs[tid] * kb[h * DH + tid];
#pragma unroll
    for (int off = 32; off > 0; off >>= 1) pb += __shfl_xor(pb, off);
    __shared__ float red[4];
    int wave = tid >> 6, lane = tid & 63;
    if (lane == 0) red[wave] = pb;
    __syncthreads();
    if (tid == 0) bavg_part[b * NH + h] = (red[0] + red[1] + red[2] + red[3]) * inv_h;
}

// ---------------------------------------------------------------------------
// Kernel 2 (heavy, streaming): register run-accumulation of patch-row vector
// sums; dot+reduce+atomic only at segment crossings (monotone advance).
// 2-row-deep software pipeline (6 KB in flight per wave), NONTEMPORAL loads
// (403 MB stream, zero reuse -> skip cache allocation), PPW=32 rows/wave,
// __launch_bounds__(256,4) caps VGPR at 128 -> 4 blocks/CU resident.
// [R6 A/B: removing nt + bound cost +17 us. Keep both.]
// grid = NB*CHUNKS (CHUNKS=32 -> 1024 blocks), 256 threads.
// ---------------------------------------------------------------------------
__global__ __launch_bounds__(256, 4) void k_score(const float* __restrict__ patch,
                                                  const float* __restrict__ w_part,
                                                  const int* __restrict__ bnd,
                                                  float* __restrict__ acc) {
    constexpr int CHUNKS = 32;
    constexpr int PPB = NP / CHUNKS;  // 128 patches per block
    constexpr int PPW = PPB / 4;      // 32 patches per wave
    constexpr int RS = DP / 4;        // row stride in f4 (192)
    int b = blockIdx.x / CHUNKS;
    int chunk = blockIdx.x % CHUNKS;
    __shared__ int bsh[NS + 1];
    int tid = threadIdx.x;
    if (tid <= NS) bsh[tid] = bnd[tid];
    __syncthreads();
    int wave = tid >> 6, lane = tid & 63;

    // weights: sum the 4 per-head partials (L2-hot)
    const f4* wp = (const f4*)(w_part + (size_t)b * NH * DP);
    f4 w0 = 0.f, w1 = 0.f, w2 = 0.f;
#pragma unroll
    for (int h = 0; h < NH; ++h) {
        w0 += wp[h * RS + lane];
        w1 += wp[h * RS + 64 + lane];
        w2 += wp[h * RS + 128 + lane];
    }
    float* accb = acc + (size_t)b * (NS + 1);

    int p0 = chunk * PPB + wave * PPW;

    // initial segment: largest i with bsh[i] <= p0; dump = NS
    int cur, nxt;
    if (p0 < bsh[0]) {
        cur = NS; nxt = bsh[0];
    } else {
        int lo = 0, hi = NS;
        while (lo < hi) {
            int mid = (lo + hi + 1) >> 1;
            if (bsh[mid] <= p0) lo = mid; else hi = mid - 1;
        }
        cur = lo;
        nxt = (cur < NS) ? bsh[cur + 1] : NP;
    }

    f4 r0 = 0.f, r1 = 0.f, r2 = 0.f;
    const f4* base = (const f4*)(patch + ((size_t)b * NP + p0) * DP);

#define LOADROW(dst0, dst1, dst2, i)                                          \
    {                                                                         \
        const f4* rp_ = base + (size_t)(i) * RS;                              \
        dst0 = __builtin_nontemporal_load(rp_ + lane);                        \
        dst1 = __builtin_nontemporal_load(rp_ + 64 + lane);                   \
        dst2 = __builtin_nontemporal_load(rp_ + 128 + lane);                  \
    }

#define PROCROW(s0, s1, s2, i)                                                \
    {                                                                         \
        int p_ = p0 + (i);                                                    \
        if (p_ >= nxt) { /* wave-uniform: flush run, advance segment */       \
            f4 sv = r0 * w0 + r1 * w1 + r2 * w2;                              \
            float s = sv.x + sv.y + sv.z + sv.w;                              \
            for (int off_ = 32; off_ > 0; off_ >>= 1) s += __shfl_xor(s, off_); \
            if (lane == 0) atomicAdd(&accb[cur], s);                          \
            r0 = 0.f; r1 = 0.f; r2 = 0.f;                                     \
            cur = (cur == NS) ? 0 : cur + 1;                                  \
            while (cur < NS && bsh[cur + 1] <= p_) cur++;                     \
            nxt = (cur < NS) ? bsh[cur + 1] : NP;                             \
        }                                                                     \
        r0 += s0; r1 += s1; r2 += s2;                                         \
    }

    f4 A0, A1, A2, B0, B1, B2, C0, C1, C2, D0, D1, D2;
    LOADROW(A0, A1, A2, 0)
    LOADROW(B0, B1, B2, 1)
#pragma unroll
    for (int g2 = 0; g2 < PPW - 2; g2 += 2) {
        LOADROW(C0, C1, C2, g2 + 2)
        LOADROW(D0, D1, D2, g2 + 3)
        PROCROW(A0, A1, A2, g2)
        PROCROW(B0, B1, B2, g2 + 1)
        A0 = C0; A1 = C1; A2 = C2;
        B0 = D0; B1 = D1; B2 = D2;
    }
    PROCROW(A0, A1, A2, PPW - 2)
    PROCROW(B0, B1, B2, PPW - 1)

    // final flush
    {
        f4 sv = r0 * w0 + r1 * w1 + r2 * w2;
        float s = sv.x + sv.y + sv.z + sv.w;
#pragma unroll
        for (int off = 32; off > 0; off >>= 1) s += __shfl_xor(s, off);
        if (lane == 0) atomicAdd(&accb[cur], s);
    }
#undef LOADROW
#undef PROCROW
}

// ---------------------------------------------------------------------------
// Kernel 3: out[b,s] = sigmoid(acc[b,s]/cnt + sum_h bavg_part[b,h]) if cnt>0
//           else sigmoid(0)
// ---------------------------------------------------------------------------
__global__ __launch_bounds__(256) void k_out(const float* __restrict__ acc,
                                             const float* __restrict__ bavg_part,
                                             const int* __restrict__ bnd,
                                             float* __restrict__ out) {
    int i = blockIdx.x * 256 + threadIdx.x;  // 0 .. NB*NS-1
    if (i >= NB * NS) return;
    int b = i / NS, s = i % NS;
    int cnt = bnd[s + 1] - bnd[s];
    float v = 0.f;
    if (cnt > 0) {
        float bb = bavg_part[b * NH] + bavg_part[b * NH + 1]
                 + bavg_part[b * NH + 2] + bavg_part[b * NH + 3];
        v = acc[b * (NS + 1) + s] / (float)cnt + bb;
    }
    out[i] = 1.0f / (1.0f + expf(-v));
}

extern "C" void kernel_launch(void* const* d_in, const int* in_sizes, int n_in,
                              void* d_out, int out_size, void* d_ws, size_t ws_size,
                              hipStream_t stream) {
    const float* h_int = (const float*)d_in[0];
    const float* h_vc  = (const float*)d_in[1];
    const float* patch = (const float*)d_in[2];
    const int*   bnd   = (const int*)d_in[3];
    const float* qW    = (const float*)d_in[4];
    const float* qb    = (const float*)d_in[5];
    const float* kW    = (const float*)d_in[6];
    const float* kb    = (const float*)d_in[7];
    float* out = (float*)d_out;

    // workspace: [acc NB*(NS+1)] [w_part NB*NH*DP] [bavg_part NB*NH]
    float* acc       = (float*)d_ws;
    float* w_part    = acc + NB * (NS + 1);
    float* bavg_part = w_part + NB * NH * DP;

    k_qw<<<NB * NH, 256, 0, stream>>>(h_int, h_vc, qW, qb, kW, kb,
                                      w_part, bavg_part, acc);
    k_score<<<NB * 32, 256, 0, stream>>>(patch, w_part, bnd, acc);
    k_out<<<(NB * NS + 255) / 256, 256, 0, stream>>>(acc, bavg_part, bnd, out);
}

// Round 8
// 91.683 us; speedup vs baseline: 1.3992x; 1.1786x over previous
//
#include <hip/hip_runtime.h>
#include <math.h>

#define NB 32
#define NP 4096
#define NS 128
#define DI 512
#define DV 512
#define DP 768
#define NH 4
#define DC 1024
#define DH 256

// clang native vector (required by __builtin_nontemporal_load; supports .xyzw)
typedef float f4 __attribute__((ext_vector_type(4)));

// ---------------------------------------------------------------------------
// Kernel A: q[b,o] = dot(h_concat[b,:], qW[o,:]) + qb[o], o = (h,d) in [0,1024)
// TLP-optimized: 4 threads per output (each DC/4 elems) + shfl reduce ->
// dependent-load chain is 8 groups (was 32). grid = NB*16 = 512 blocks.
// Also: zeroes acc[], emits per-block bias partials bavg_part[b*16+g]
// (no atomics -> no pre-zero needed).
// ---------------------------------------------------------------------------
__global__ __launch_bounds__(256) void k_q2(const float* __restrict__ h_int,
                                            const float* __restrict__ h_vc,
                                            const float* __restrict__ qW,
                                            const float* __restrict__ qb,
                                            const float* __restrict__ kb,
                                            float* __restrict__ q,
                                            float* __restrict__ bavg_part,
                                            float* __restrict__ acc) {
    int b = blockIdx.x >> 4, g = blockIdx.x & 15;
    int tid = threadIdx.x;

    // zero the k_score accumulator (4128 elements < 512*256 threads)
    int zi = blockIdx.x * 256 + tid;
    if (zi < NB * (NS + 1)) acc[zi] = 0.f;

    __shared__ float hc[DC];
    for (int i = tid; i < DI; i += 256) hc[i] = h_int[b * DI + i];
    for (int i = tid; i < DV; i += 256) hc[DI + i] = h_vc[b * DV + i];
    __syncthreads();

    int j = tid >> 2, r = tid & 3;   // j: output within block, r: DC-quarter
    int o = g * 64 + j;              // global output index (h = o>>8, d = o&255)
    const float* w = qW + (size_t)o * DC + r * 256;
    const float* hq = hc + r * 256;
    float s = 0.f;
#pragma unroll 8
    for (int c = 0; c < 256; c += 4) {
        f4 wv = *(const f4*)(w + c);
        s += wv.x * hq[c] + wv.y * hq[c + 1] + wv.z * hq[c + 2] + wv.w * hq[c + 3];
    }
    // reduce the 4 quarter-partials (lanes j*4 .. j*4+3)
    s += __shfl_xor(s, 1);
    s += __shfl_xor(s, 2);
    float qv = s + qb[o];

    __shared__ float red[64];
    if (r == 0) {
        q[(size_t)b * (NH * DH) + o] = qv;
        red[j] = qv * kb[o];         // bias partial (1/H applied in k_out)
    }
    __syncthreads();
    if (tid == 0) {
        float t = 0.f;
        for (int i = 0; i < 64; ++i) t += red[i];
        bavg_part[b * 16 + g] = t;
    }
}

// ---------------------------------------------------------------------------
// Kernel B: w_part[b,h,c] = (1/H) * sum_d q[b,h,d] * kW[h,d,c]
// grid = NB*NH*3 (column chunks of 256). Threads: rc (row-chunk, 4) x cg
// (f4 col-group, 64); 4-way row split + LDS reduce -> chain = 8 groups.
// kW reads fully coalesced (1 KB / wave instruction).
// ---------------------------------------------------------------------------
__global__ __launch_bounds__(256) void k_w2(const float* __restrict__ q,
                                            const float* __restrict__ kW,
                                            float* __restrict__ w_part) {
    int bid = blockIdx.x;
    int cc = bid % 3, bh = bid / 3;
    int h = bh % NH, b = bh / NH;
    int tid = threadIdx.x;

    __shared__ float qs[DH];
    __shared__ f4 part[4][64];
    if (tid < DH) qs[tid] = q[(size_t)b * (NH * DH) + h * DH + tid];
    __syncthreads();

    int rc = tid >> 6, cg = tid & 63;
    const float* kbase = kW + (size_t)(h * DH + rc * 64) * DP + cc * 256 + cg * 4;
    const float* qr = qs + rc * 64;
    f4 wacc = 0.f;
#pragma unroll 8
    for (int i = 0; i < 64; ++i) {
        f4 kv = *(const f4*)(kbase + (size_t)i * DP);
        wacc += qr[i] * kv;
    }
    part[rc][cg] = wacc;
    __syncthreads();
    if (rc == 0) {
        f4 t = (part[0][cg] + part[1][cg]) + (part[2][cg] + part[3][cg]);
        *(f4*)(w_part + (size_t)(b * NH + h) * DP + cc * 256 + cg * 4) =
            t * (1.0f / NH);
    }
}

// ---------------------------------------------------------------------------
// Kernel 2 (heavy, streaming): register run-accumulation of patch-row vector
// sums; dot+reduce+atomic only at segment crossings (monotone advance).
// 2-row-deep software pipeline (6 KB in flight per wave), NONTEMPORAL loads
// (403 MB stream, zero reuse -> skip cache allocation), PPW=32 rows/wave,
// __launch_bounds__(256,4) caps VGPR at 128 -> 4 blocks/CU resident.
// [R6 A/B: removing nt + bound cost +17 us. Keep both. UNCHANGED from R7.]
// grid = NB*CHUNKS (CHUNKS=32 -> 1024 blocks), 256 threads.
// ---------------------------------------------------------------------------
__global__ __launch_bounds__(256, 4) void k_score(const float* __restrict__ patch,
                                                  const float* __restrict__ w_part,
                                                  const int* __restrict__ bnd,
                                                  float* __restrict__ acc) {
    constexpr int CHUNKS = 32;
    constexpr int PPB = NP / CHUNKS;  // 128 patches per block
    constexpr int PPW = PPB / 4;      // 32 patches per wave
    constexpr int RS = DP / 4;        // row stride in f4 (192)
    int b = blockIdx.x / CHUNKS;
    int chunk = blockIdx.x % CHUNKS;
    __shared__ int bsh[NS + 1];
    int tid = threadIdx.x;
    if (tid <= NS) bsh[tid] = bnd[tid];
    __syncthreads();
    int wave = tid >> 6, lane = tid & 63;

    // weights: sum the 4 per-head partials (L2-hot)
    const f4* wp = (const f4*)(w_part + (size_t)b * NH * DP);
    f4 w0 = 0.f, w1 = 0.f, w2 = 0.f;
#pragma unroll
    for (int h = 0; h < NH; ++h) {
        w0 += wp[h * RS + lane];
        w1 += wp[h * RS + 64 + lane];
        w2 += wp[h * RS + 128 + lane];
    }
    float* accb = acc + (size_t)b * (NS + 1);

    int p0 = chunk * PPB + wave * PPW;

    // initial segment: largest i with bsh[i] <= p0; dump = NS
    int cur, nxt;
    if (p0 < bsh[0]) {
        cur = NS; nxt = bsh[0];
    } else {
        int lo = 0, hi = NS;
        while (lo < hi) {
            int mid = (lo + hi + 1) >> 1;
            if (bsh[mid] <= p0) lo = mid; else hi = mid - 1;
        }
        cur = lo;
        nxt = (cur < NS) ? bsh[cur + 1] : NP;
    }

    f4 r0 = 0.f, r1 = 0.f, r2 = 0.f;
    const f4* base = (const f4*)(patch + ((size_t)b * NP + p0) * DP);

#define LOADROW(dst0, dst1, dst2, i)                                          \
    {                                                                         \
        const f4* rp_ = base + (size_t)(i) * RS;                              \
        dst0 = __builtin_nontemporal_load(rp_ + lane);                        \
        dst1 = __builtin_nontemporal_load(rp_ + 64 + lane);                   \
        dst2 = __builtin_nontemporal_load(rp_ + 128 + lane);                  \
    }

#define PROCROW(s0, s1, s2, i)                                                \
    {                                                                         \
        int p_ = p0 + (i);                                                    \
        if (p_ >= nxt) { /* wave-uniform: flush run, advance segment */       \
            f4 sv = r0 * w0 + r1 * w1 + r2 * w2;                              \
            float s = sv.x + sv.y + sv.z + sv.w;                              \
            for (int off_ = 32; off_ > 0; off_ >>= 1) s += __shfl_xor(s, off_); \
            if (lane == 0) atomicAdd(&accb[cur], s);                          \
            r0 = 0.f; r1 = 0.f; r2 = 0.f;                                     \
            cur = (cur == NS) ? 0 : cur + 1;                                  \
            while (cur < NS && bsh[cur + 1] <= p_) cur++;                     \
            nxt = (cur < NS) ? bsh[cur + 1] : NP;                             \
        }                                                                     \
        r0 += s0; r1 += s1; r2 += s2;                                         \
    }

    f4 A0, A1, A2, B0, B1, B2, C0, C1, C2, D0, D1, D2;
    LOADROW(A0, A1, A2, 0)
    LOADROW(B0, B1, B2, 1)
#pragma unroll
    for (int g2 = 0; g2 < PPW - 2; g2 += 2) {
        LOADROW(C0, C1, C2, g2 + 2)
        LOADROW(D0, D1, D2, g2 + 3)
        PROCROW(A0, A1, A2, g2)
        PROCROW(B0, B1, B2, g2 + 1)
        A0 = C0; A1 = C1; A2 = C2;
        B0 = D0; B1 = D1; B2 = D2;
    }
    PROCROW(A0, A1, A2, PPW - 2)
    PROCROW(B0, B1, B2, PPW - 1)

    // final flush
    {
        f4 sv = r0 * w0 + r1 * w1 + r2 * w2;
        float s = sv.x + sv.y + sv.z + sv.w;
#pragma unroll
        for (int off = 32; off > 0; off >>= 1) s += __shfl_xor(s, off);
        if (lane == 0) atomicAdd(&accb[cur], s);
    }
#undef LOADROW
#undef PROCROW
}

// ---------------------------------------------------------------------------
// Kernel 3: out[b,s] = sigmoid(acc[b,s]/cnt + (1/H)*sum_g bavg_part[b,g])
//           if cnt>0 else sigmoid(0)
// ---------------------------------------------------------------------------
__global__ __launch_bounds__(256) void k_out(const float* __restrict__ acc,
                                             const float* __restrict__ bavg_part,
                                             const int* __restrict__ bnd,
                                             float* __restrict__ out) {
    int i = blockIdx.x * 256 + threadIdx.x;  // 0 .. NB*NS-1
    if (i >= NB * NS) return;
    int b = i / NS, s = i % NS;
    int cnt = bnd[s + 1] - bnd[s];
    float v = 0.f;
    if (cnt > 0) {
        float bb = 0.f;
#pragma unroll
        for (int g = 0; g < 16; ++g) bb += bavg_part[b * 16 + g];
        v = acc[b * (NS + 1) + s] / (float)cnt + bb * (1.0f / NH);
    }
    out[i] = 1.0f / (1.0f + expf(-v));
}

extern "C" void kernel_launch(void* const* d_in, const int* in_sizes, int n_in,
                              void* d_out, int out_size, void* d_ws, size_t ws_size,
                              hipStream_t stream) {
    const float* h_int = (const float*)d_in[0];
    const float* h_vc  = (const float*)d_in[1];
    const float* patch = (const float*)d_in[2];
    const int*   bnd   = (const int*)d_in[3];
    const float* qW    = (const float*)d_in[4];
    const float* qb    = (const float*)d_in[5];
    const float* kW    = (const float*)d_in[6];
    const float* kb    = (const float*)d_in[7];
    float* out = (float*)d_out;

    // workspace: [acc NB*(NS+1)] [w_part NB*NH*DP] [bavg_part NB*16] [q NB*1024]
    float* acc       = (float*)d_ws;
    float* w_part    = acc + NB * (NS + 1);
    float* bavg_part = w_part + NB * NH * DP;
    float* q         = bavg_part + NB * 16;

    k_q2<<<NB * 16, 256, 0, stream>>>(h_int, h_vc, qW, qb, kb, q, bavg_part, acc);
    k_w2<<<NB * NH * 3, 256, 0, stream>>>(q, kW, w_part);
    k_score<<<NB * 32, 256, 0, stream>>>(patch, w_part, bnd, acc);
    k_out<<<(NB * NS + 255) / 256, 256, 0, stream>>>(acc, bavg_part, bnd, out);
}